// Round 1
// 804.459 us; speedup vs baseline: 1.1075x; 1.1075x over previous
//
#include <hip/hip_runtime.h>
#include <cstdint>
#include <cstddef>

typedef unsigned short u16;
typedef __bf16 bf16x8 __attribute__((ext_vector_type(8)));
typedef float f32x4 __attribute__((ext_vector_type(4)));
typedef u16 u16x8 __attribute__((ext_vector_type(8)));

#define B_DIM 4096
#define H_DIM 2048
#define BH 8388608  // B_DIM * H_DIM

__device__ __forceinline__ float b2f(u16 x) {
  union { uint32_t u; float f; } v;
  v.u = ((uint32_t)x) << 16;
  return v.f;
}
__device__ __forceinline__ u16 f2b(float f) {
  union { float f; uint32_t u; } v;
  v.f = f;
  uint32_t r = v.u + 0x7FFFu + ((v.u >> 16) & 1u);
  return (u16)(r >> 16);
}
__device__ __forceinline__ float sigm(float x) { return 1.0f / (1.0f + __expf(-x)); }

typedef __attribute__((address_space(1))) void gv_t;
typedef __attribute__((address_space(3))) void lv_t;
__device__ __forceinline__ void g2lds16(const void* g, void* l) {
  __builtin_amdgcn_global_load_lds((gv_t*)g, (lv_t*)l, 16, 0, 0);
}

#define MFMA_BF16 __builtin_amdgcn_mfma_f32_16x16x32_bf16

// ---------------- fp32 -> bf16 activation convert ----------------
struct CvtParams { const float* src[3]; u16* dst[3]; };

__global__ __launch_bounds__(256) void cvt_k(CvtParams p) {
  const float* __restrict__ s = p.src[blockIdx.y];
  u16* __restrict__ d = p.dst[blockIdx.y];
  size_t idx = ((size_t)blockIdx.x * 256 + threadIdx.x) * 8;
  float4 a = *(const float4*)(s + idx);
  float4 b = *(const float4*)(s + idx + 4);
  u16x8 o;
  o[0] = f2b(a.x); o[1] = f2b(a.y); o[2] = f2b(a.z); o[3] = f2b(a.w);
  o[4] = f2b(b.x); o[5] = f2b(b.y); o[6] = f2b(b.z); o[7] = f2b(b.w);
  *(u16x8*)(d + idx) = o;
}

// ---------------- weight transpose+convert: Wt[n][k] = bf16(W[k][n]) ----------------
struct TransParams {
  const float* src[13];
  u16* dst[13];
  int dstride[13];
};

__global__ __launch_bounds__(256) void transpose_k(TransParams p) {
  __shared__ u16 lds[64][72];  // pitch 72 breaks bank aliasing
  const int mat = blockIdx.z;
  const float* __restrict__ src = p.src[mat];
  u16* __restrict__ dst = p.dst[mat];
  const int dstride = p.dstride[mat];
  const int tk = blockIdx.y * 64;
  const int tn = blockIdx.x * 64;
  const int t = threadIdx.x;
  const int lr = t >> 3;
  const int lc = (t & 7) * 8;
#pragma unroll
  for (int half = 0; half < 2; half++) {
    int r = lr + half * 32;
    const float4* g = (const float4*)(src + (size_t)(tk + r) * 2048 + tn + lc);
    float4 a = g[0], b = g[1];
    u16x8 t8;
    t8[0] = f2b(a.x); t8[1] = f2b(a.y); t8[2] = f2b(a.z); t8[3] = f2b(a.w);
    t8[4] = f2b(b.x); t8[5] = f2b(b.y); t8[6] = f2b(b.z); t8[7] = f2b(b.w);
    *(u16x8*)&lds[r][lc] = t8;
  }
  __syncthreads();
#pragma unroll
  for (int half = 0; half < 2; half++) {
    int n = lr + half * 32;
    u16x8 tmp;
#pragma unroll
    for (int j = 0; j < 8; j++) tmp[j] = lds[lc + j][n];
    *(u16x8*)(dst + (size_t)(tn + n) * dstride + tk + lc) = tmp;
  }
}

// ---------------- 256x256-tile, BK=64, 8-wave, 4-phase/tile pipelined K-loop ----------------
// LDS per buffer: A 256x64 bf16 (XOR-swizzled: 16B chunk c of row r at slot c^(r&7)),
// B 256x64. Two buffers (128 KiB). Per tile t (buf p=t&1):
//   ph1: ds_read A-ks0(8)+B-ks0(4); stage B0,B1(t+1)->buf q; bar; lgkm0; 16 MFMA (ks0,j01); bar
//   ph2: stage B2,B3(t+1)->q;                               bar;        16 MFMA (ks0,j23); bar
//   ph3: ds_read A-ks1(8)+B-ks1(4);                         bar; lgkm0; 16 MFMA (ks1,j01); bar
//   ph4: stage A0-3(t+2)->p (A region of p dead after ph3); bar; 16 MFMA (ks1,j23);
//        vmcnt(4)  [newest 4 = t+2's A stages; everything tile t+1 needs is older]; bar
// vmcnt never drains to 0 in the main loop; raw s_barrier (no implicit waitcnt drain).
__device__ __forceinline__ void kloop256(
    const u16* __restrict__ A0, const u16* __restrict__ A1, const u16* __restrict__ A2,
    const u16* __restrict__ Wt, const int NT, const long Ktot,
    const int m0, const int n0,
    u16* lA0, u16* lA1, u16* lB0, u16* lB1,
    f32x4 (&acc)[8][4]) {
  const int tid = threadIdx.x;
  const int wave = tid >> 6, lane = tid & 63;
  const int fm = lane & 15, fkc = lane >> 4;
  const int x7 = fm & 7;
  const int wm = (wave >> 2) * 128, wn = (wave & 3) * 64;
  const int lr = tid >> 3;                 // 0..63 row-in-round
  const int chunk = (tid & 7) ^ (lr & 7);  // pre-swizzled global k-chunk
  const int stageOff = wave * 512;         // wave*8 rows * 64 elems

  int raOff[8], rbOff[4];
#pragma unroll
  for (int i = 0; i < 8; i++) raOff[i] = (wm + i * 16 + fm) * 64;
#pragma unroll
  for (int j = 0; j < 4; j++) rbOff[j] = (wn + j * 16 + fm) * 64;
  const int so0 = ((fkc ^ x7) << 3);        // ks0 chunk c=fkc
  const int so1 = (((4 + fkc) ^ x7) << 3);  // ks1 chunk c=4+fkc

  auto stA = [&](int tt, int a, u16* dst) {
    const int seg = tt >> 5;
    const u16* base = (seg == 0) ? A0 : ((seg == 1) ? A1 : A2);
    const u16* src = base + (size_t)(m0 + a * 64 + lr) * 2048 + ((tt & 31) << 6) + (chunk << 3);
    g2lds16(src, dst + a * 4096 + stageOff);
  };
  auto stB = [&](int tt, int b, u16* dst) {
    const u16* src = Wt + (size_t)(n0 + b * 64 + lr) * Ktot + ((size_t)tt << 6) + (chunk << 3);
    g2lds16(src, dst + b * 4096 + stageOff);
  };

  // prologue: tile0 (A+B) -> buf0; tile1 A -> buf1; wait tile0 landed (4 newest may fly)
#pragma unroll
  for (int a = 0; a < 4; a++) stA(0, a, lA0);
#pragma unroll
  for (int b = 0; b < 4; b++) stB(0, b, lB0);
  const int t1p = (1 < NT) ? 1 : 0;
#pragma unroll
  for (int a = 0; a < 4; a++) stA(t1p, a, lA1);
  asm volatile("s_waitcnt vmcnt(4)" ::: "memory");
  __builtin_amdgcn_sched_barrier(0);
  __builtin_amdgcn_s_barrier();
  __builtin_amdgcn_sched_barrier(0);

  for (int t = 0; t < NT; ++t) {
    u16* lAp = (t & 1) ? lA1 : lA0;
    u16* lBp = (t & 1) ? lB1 : lB0;
    u16* lBq = (t & 1) ? lB0 : lB1;
    const int tn1 = (t + 1 < NT) ? t + 1 : NT - 1;
    const int tn2 = (t + 2 < NT) ? t + 2 : NT - 1;

    // ---- phase 1
    bf16x8 a0[8], b0[4];
#pragma unroll
    for (int i = 0; i < 8; i++) a0[i] = *(const bf16x8*)&lAp[raOff[i] + so0];
#pragma unroll
    for (int j = 0; j < 4; j++) b0[j] = *(const bf16x8*)&lBp[rbOff[j] + so0];
    stB(tn1, 0, lBq);
    stB(tn1, 1, lBq);
    __builtin_amdgcn_s_barrier();
    asm volatile("s_waitcnt lgkmcnt(0)" ::: "memory");
    __builtin_amdgcn_sched_barrier(0);
    __builtin_amdgcn_s_setprio(1);
#pragma unroll
    for (int i = 0; i < 8; i++) {
      acc[i][0] = MFMA_BF16(a0[i], b0[0], acc[i][0], 0, 0, 0);
      acc[i][1] = MFMA_BF16(a0[i], b0[1], acc[i][1], 0, 0, 0);
    }
    __builtin_amdgcn_s_setprio(0);
    __builtin_amdgcn_sched_barrier(0);
    __builtin_amdgcn_s_barrier();
    __builtin_amdgcn_sched_barrier(0);

    // ---- phase 2
    stB(tn1, 2, lBq);
    stB(tn1, 3, lBq);
    __builtin_amdgcn_s_barrier();
    __builtin_amdgcn_sched_barrier(0);
    __builtin_amdgcn_s_setprio(1);
#pragma unroll
    for (int i = 0; i < 8; i++) {
      acc[i][2] = MFMA_BF16(a0[i], b0[2], acc[i][2], 0, 0, 0);
      acc[i][3] = MFMA_BF16(a0[i], b0[3], acc[i][3], 0, 0, 0);
    }
    __builtin_amdgcn_s_setprio(0);
    __builtin_amdgcn_sched_barrier(0);
    __builtin_amdgcn_s_barrier();
    __builtin_amdgcn_sched_barrier(0);

    // ---- phase 3
    bf16x8 a1[8], b1[4];
#pragma unroll
    for (int i = 0; i < 8; i++) a1[i] = *(const bf16x8*)&lAp[raOff[i] + so1];
#pragma unroll
    for (int j = 0; j < 4; j++) b1[j] = *(const bf16x8*)&lBp[rbOff[j] + so1];
    __builtin_amdgcn_s_barrier();
    asm volatile("s_waitcnt lgkmcnt(0)" ::: "memory");
    __builtin_amdgcn_sched_barrier(0);
    __builtin_amdgcn_s_setprio(1);
#pragma unroll
    for (int i = 0; i < 8; i++) {
      acc[i][0] = MFMA_BF16(a1[i], b1[0], acc[i][0], 0, 0, 0);
      acc[i][1] = MFMA_BF16(a1[i], b1[1], acc[i][1], 0, 0, 0);
    }
    __builtin_amdgcn_s_setprio(0);
    __builtin_amdgcn_sched_barrier(0);
    __builtin_amdgcn_s_barrier();
    __builtin_amdgcn_sched_barrier(0);

    // ---- phase 4
    stA(tn2, 0, lAp);
    stA(tn2, 1, lAp);
    stA(tn2, 2, lAp);
    stA(tn2, 3, lAp);
    __builtin_amdgcn_s_barrier();
    __builtin_amdgcn_sched_barrier(0);
    __builtin_amdgcn_s_setprio(1);
#pragma unroll
    for (int i = 0; i < 8; i++) {
      acc[i][2] = MFMA_BF16(a1[i], b1[2], acc[i][2], 0, 0, 0);
      acc[i][3] = MFMA_BF16(a1[i], b1[3], acc[i][3], 0, 0, 0);
    }
    __builtin_amdgcn_s_setprio(0);
    asm volatile("s_waitcnt vmcnt(4)" ::: "memory");
    __builtin_amdgcn_sched_barrier(0);
    __builtin_amdgcn_s_barrier();
    __builtin_amdgcn_sched_barrier(0);
  }
}

// ---------------- phase-1 GEMMs (fused K; grid.z = gate) ----------------
struct Gemm256Desc {
  const u16* A0; const u16* A1; const u16* A2;
  const u16* Wt; u16* C; int nseg;
};
struct Gemm256Params { Gemm256Desc d[5]; };

__global__ __launch_bounds__(512) void gemm256_multi(Gemm256Params p) {
  const Gemm256Desc d = p.d[blockIdx.z];
  __shared__ u16 lA[2][16384];
  __shared__ u16 lB[2][16384];
  // XCD-aware swizzle within the 128-block z-slice (bijective: 128 % 8 == 0)
  const int bid = blockIdx.y * 8 + blockIdx.x;
  const int swz = (bid & 7) * 16 + (bid >> 3);
  const int m0 = (swz >> 3) * 256, n0 = (swz & 7) * 256;
  const int NT = d.nseg << 5;
  const long Ktot = (long)NT << 6;

  f32x4 acc[8][4];
#pragma unroll
  for (int i = 0; i < 8; i++)
#pragma unroll
    for (int j = 0; j < 4; j++) acc[i][j] = (f32x4)0.0f;

  kloop256(d.A0, d.A1, d.A2, d.Wt, NT, Ktot, m0, n0, lA[0], lA[1], lB[0], lB[1], acc);

  const int lane = threadIdx.x & 63, wave = threadIdx.x >> 6;
  const int fm = lane & 15, quad = lane >> 4;
  const int wm = (wave >> 2) * 128, wn = (wave & 3) * 64;
#pragma unroll
  for (int i = 0; i < 8; i++)
#pragma unroll
    for (int j = 0; j < 4; j++)
#pragma unroll
      for (int r = 0; r < 4; r++) {
        size_t row = (size_t)(m0 + wm + i * 16 + quad * 4 + r);
        size_t col = (size_t)(n0 + wn + j * 16 + fm);
        d.C[row * 2048 + col] = f2b(acc[i][j][r]);
      }
}

// ---------------- phase-3 GEMMs: z=0: t1=c@w_co (bf16); z=1: t2=tanh(c)@w_c (fp32) ----------------
struct GemmResParams {
  const u16* A[2]; const u16* W[2];
  u16* t1; float* t2;
};

__global__ __launch_bounds__(512) void gemm256_res(GemmResParams p) {
  const int z = blockIdx.z;
  __shared__ u16 lA[2][16384];
  __shared__ u16 lB[2][16384];
  const int bid = blockIdx.y * 8 + blockIdx.x;
  const int swz = (bid & 7) * 16 + (bid >> 3);
  const int m0 = (swz >> 3) * 256, n0 = (swz & 7) * 256;

  f32x4 acc[8][4];
#pragma unroll
  for (int i = 0; i < 8; i++)
#pragma unroll
    for (int j = 0; j < 4; j++) acc[i][j] = (f32x4)0.0f;

  kloop256(p.A[z], nullptr, nullptr, p.W[z], 32, 2048, m0, n0, lA[0], lA[1], lB[0], lB[1], acc);

  const int lane = threadIdx.x & 63, wave = threadIdx.x >> 6;
  const int fm = lane & 15, quad = lane >> 4;
  const int wm = (wave >> 2) * 128, wn = (wave & 3) * 64;
  if (z == 0) {
#pragma unroll
    for (int i = 0; i < 8; i++)
#pragma unroll
      for (int j = 0; j < 4; j++)
#pragma unroll
        for (int r = 0; r < 4; r++) {
          size_t row = (size_t)(m0 + wm + i * 16 + quad * 4 + r);
          size_t col = (size_t)(n0 + wn + j * 16 + fm);
          p.t1[row * 2048 + col] = f2b(acc[i][j][r]);
        }
  } else {
#pragma unroll
    for (int i = 0; i < 8; i++)
#pragma unroll
      for (int j = 0; j < 4; j++)
#pragma unroll
        for (int r = 0; r < 4; r++) {
          size_t row = (size_t)(m0 + wm + i * 16 + quad * 4 + r);
          size_t col = (size_t)(n0 + wn + j * 16 + fm);
          p.t2[row * 2048 + col] = acc[i][j][r];
        }
  }
}

// ---------------- elementwise 1: gates -> c; stash bf16(c), bf16(tanh c) in-place ----------------
__global__ __launch_bounds__(256) void ew1_k(
    u16* __restrict__ zi, const u16* __restrict__ zf, u16* __restrict__ zg,
    const float* __restrict__ cprev, const float* __restrict__ bi,
    const float* __restrict__ bff, const float* __restrict__ bg,
    float* __restrict__ c_out) {
  size_t idx = ((size_t)blockIdx.x * 256 + threadIdx.x) * 8;
  int col = (int)(idx & (H_DIM - 1));
  u16x8 vzi = *(const u16x8*)(zi + idx);
  u16x8 vzf = *(const u16x8*)(zf + idx);
  u16x8 vzg = *(const u16x8*)(zg + idx);
  float4 cp0 = *(const float4*)(cprev + idx);
  float4 cp1 = *(const float4*)(cprev + idx + 4);
  float4 bi0 = *(const float4*)(bi + col), bi1 = *(const float4*)(bi + col + 4);
  float4 bf0 = *(const float4*)(bff + col), bf1 = *(const float4*)(bff + col + 4);
  float4 bg0 = *(const float4*)(bg + col), bg1 = *(const float4*)(bg + col + 4);
  float cpv[8] = {cp0.x, cp0.y, cp0.z, cp0.w, cp1.x, cp1.y, cp1.z, cp1.w};
  float biv[8] = {bi0.x, bi0.y, bi0.z, bi0.w, bi1.x, bi1.y, bi1.z, bi1.w};
  float bfv[8] = {bf0.x, bf0.y, bf0.z, bf0.w, bf1.x, bf1.y, bf1.z, bf1.w};
  float bgv[8] = {bg0.x, bg0.y, bg0.z, bg0.w, bg1.x, bg1.y, bg1.z, bg1.w};
  float cv[8], tcv[8];
#pragma unroll
  for (int e = 0; e < 8; e++) {
    float iv = b2f(vzi[e]) + biv[e];
    float fv = b2f(vzf[e]) + bfv[e];
    float gv = b2f(vzg[e]) + bgv[e];
    float c = sigm(fv) * cpv[e] + sigm(iv) * tanhf(gv);
    cv[e] = c;
    tcv[e] = tanhf(c);
  }
  u16x8 cb8, tc8;
#pragma unroll
  for (int e = 0; e < 8; e++) { cb8[e] = f2b(cv[e]); tc8[e] = f2b(tcv[e]); }
  *(u16x8*)(zi + idx) = cb8;   // bf16(c) for c @ w_co
  *(u16x8*)(zg + idx) = tc8;   // bf16(tanh c) for tanh(c) @ w_c
  float4 c0 = {cv[0], cv[1], cv[2], cv[3]}, c1 = {cv[4], cv[5], cv[6], cv[7]};
  *(float4*)(c_out + idx) = c0;
  *(float4*)(c_out + idx + 4) = c1;
}

// ---------------- elementwise 2: h = tanh(zo + t1 + b_o) * (zr + t2) ----------------
__global__ __launch_bounds__(256) void ew2_k(
    const u16* __restrict__ zo, const u16* __restrict__ zr,
    const u16* __restrict__ t1, const float* __restrict__ t2,
    const float* __restrict__ bo, float* __restrict__ h) {
  size_t idx = ((size_t)blockIdx.x * 256 + threadIdx.x) * 8;
  int col = (int)(idx & (H_DIM - 1));
  u16x8 vo = *(const u16x8*)(zo + idx);
  u16x8 vr = *(const u16x8*)(zr + idx);
  u16x8 v1 = *(const u16x8*)(t1 + idx);
  float4 t2a = *(const float4*)(t2 + idx);
  float4 t2b = *(const float4*)(t2 + idx + 4);
  float4 bo0 = *(const float4*)(bo + col);
  float4 bo1 = *(const float4*)(bo + col + 4);
  float t2v[8] = {t2a.x, t2a.y, t2a.z, t2a.w, t2b.x, t2b.y, t2b.z, t2b.w};
  float bov[8] = {bo0.x, bo0.y, bo0.z, bo0.w, bo1.x, bo1.y, bo1.z, bo1.w};
  float hv[8];
#pragma unroll
  for (int e = 0; e < 8; e++) {
    float ov = b2f(vo[e]) + b2f(v1[e]) + bov[e];
    hv[e] = tanhf(ov) * (b2f(vr[e]) + t2v[e]);
  }
  float4 h0 = {hv[0], hv[1], hv[2], hv[3]}, h1 = {hv[4], hv[5], hv[6], hv[7]};
  *(float4*)(h + idx) = h0;
  *(float4*)(h + idx + 4) = h1;
}

// ---------------- launch ----------------
extern "C" void kernel_launch(void* const* d_in, const int* in_sizes, int n_in,
                              void* d_out, int out_size, void* d_ws, size_t ws_size,
                              hipStream_t stream) {
  const float* input_ = (const float*)d_in[0];
  const float* h_prev = (const float*)d_in[1];
  const float* c_prev = (const float*)d_in[2];
  const float* w_xi = (const float*)d_in[3];
  const float* w_hi = (const float*)d_in[4];
  const float* w_ci = (const float*)d_in[5];
  const float* w_xf = (const float*)d_in[6];
  const float* w_hf = (const float*)d_in[7];
  const float* w_cf = (const float*)d_in[8];
  const float* w_xg = (const float*)d_in[9];
  const float* w_hg = (const float*)d_in[10];
  const float* w_xo = (const float*)d_in[11];
  const float* w_ho = (const float*)d_in[12];
  const float* w_co = (const float*)d_in[13];
  const float* w_c  = (const float*)d_in[14];
  const float* w_i  = (const float*)d_in[15];
  const float* b_i  = (const float*)d_in[16];
  const float* b_f  = (const float*)d_in[17];
  const float* b_g  = (const float*)d_in[18];
  const float* b_o  = (const float*)d_in[19];

  u16* ws = (u16*)d_ws;
  u16* WtI  = ws;                          // 2048 x 6144  [n][k: xi|hi|ci]
  u16* WtF  = WtI  + (size_t)2048 * 6144;
  u16* WtG  = WtF  + (size_t)2048 * 6144;  // 2048 x 4096  [n][k: xg|hg]
  u16* WtO  = WtG  + (size_t)2048 * 4096;
  u16* WtR  = WtO  + (size_t)2048 * 4096;  // 2048 x 2048
  u16* WtCO = WtR  + (size_t)2048 * 2048;
  u16* WtC  = WtCO + (size_t)2048 * 2048;
  u16* zi   = WtC  + (size_t)2048 * 2048;  // [4096 x 2048] bf16 each
  u16* zf   = zi + (size_t)BH;
  u16* zg   = zf + (size_t)BH;
  u16* zo   = zg + (size_t)BH;
  u16* zr   = zo + (size_t)BH;

  // t1 (bf16) reuses WtG (dead after gemm256_multi; exactly BH elems).
  // t2 (fp32) reuses WtI+WtF (dead after gemm256_multi; 50 MB >= 33.6 MB).
  u16* t1buf = WtG;
  float* t2buf = (float*)WtI;

  u16* ob16 = (u16*)d_out;
  u16* xb = ob16;                  // bf16(input_)  — dead before h written
  u16* hb = ob16 + (size_t)BH;     // bf16(h_prev)
  u16* cb = ob16 + (size_t)2 * BH; // bf16(c_prev)  — dead before c written
  float* out_f = (float*)d_out;
  float* h_out = out_f;
  float* c_out = out_f + (size_t)BH;

  // 1. activations fp32 -> bf16
  CvtParams cp;
  cp.src[0] = input_; cp.src[1] = h_prev; cp.src[2] = c_prev;
  cp.dst[0] = xb; cp.dst[1] = hb; cp.dst[2] = cb;
  cvt_k<<<dim3(BH / 2048, 3), 256, 0, stream>>>(cp);

  // 2. weights fp32 -> bf16, transposed into fused-K layouts
  TransParams tp;
  const float* srcs[13] = {w_xi, w_hi, w_ci, w_xf, w_hf, w_cf, w_xg, w_hg, w_xo, w_ho, w_i, w_co, w_c};
  u16* dsts[13] = {WtI, WtI + 2048, WtI + 4096, WtF, WtF + 2048, WtF + 4096,
                   WtG, WtG + 2048, WtO, WtO + 2048, WtR, WtCO, WtC};
  int strides[13] = {6144, 6144, 6144, 6144, 6144, 6144, 4096, 4096, 4096, 4096, 2048, 2048, 2048};
  for (int i = 0; i < 13; i++) { tp.src[i] = srcs[i]; tp.dst[i] = dsts[i]; tp.dstride[i] = strides[i]; }
  transpose_k<<<dim3(32, 32, 13), 256, 0, stream>>>(tp);

  // 3. phase-1 GEMMs (fused K; 256x256 tiles, 8-phase pipelined)
  Gemm256Params g1;
  g1.d[0] = {xb, hb, cb, WtI, zi, 3};
  g1.d[1] = {xb, hb, cb, WtF, zf, 3};
  g1.d[2] = {xb, hb, nullptr, WtG, zg, 2};
  g1.d[3] = {xb, hb, nullptr, WtO, zo, 2};
  g1.d[4] = {xb, nullptr, nullptr, WtR, zr, 1};
  gemm256_multi<<<dim3(8, 16, 5), 512, 0, stream>>>(g1);

  // 4. elementwise 1: c fp32 -> d_out; bf16(c) -> zi, bf16(tanh c) -> zg (in-place)
  ew1_k<<<dim3(BH / 2048), 256, 0, stream>>>(zi, zf, zg, c_prev, b_i, b_f, b_g, c_out);

  // 5. phase-3 GEMMs: z=0 t1 = c@w_co (bf16), z=1 t2 = tanh(c)@w_c (fp32)
  GemmResParams gr;
  gr.A[0] = zi; gr.A[1] = zg; gr.W[0] = WtCO; gr.W[1] = WtC;
  gr.t1 = t1buf; gr.t2 = t2buf;
  gemm256_res<<<dim3(8, 16, 2), 512, 0, stream>>>(gr);

  // 6. elementwise 2: h -> d_out
  ew2_k<<<dim3(BH / 2048), 256, 0, stream>>>(zo, zr, t1buf, t2buf, b_o, h_out);
}